// Round 9
// baseline (292.750 us; speedup 1.0000x reference)
//
#include <hip/hip_runtime.h>

// ---------------------------------------------------------------------------
// SpatialSelfCrossAttention  (B=32, C=256, H=W=32, N=1024)
// I/O fp32, internal bf16 MFMA (fp32 accum).
//
// Round-13 changes (kattn main loop only):
//  * Counted-vmcnt sync (T4): per iter = raw s_barrier (buf free) -> issue 6
//    DMAs -> s_waitcnt vmcnt(6) (own tile loads done; NEXT tile's 6 loads
//    stay in flight across the barrier) -> raw s_barrier (all waves landed)
//    -> compute. Replaces __syncthreads whose vmcnt(0) drain killed the
//    prefetch every iteration. Last iter waits vmcnt(0).
//  * ktp (merged trans+prep) / kproj (r10 gemm_core) / epilogue unchanged.
// ---------------------------------------------------------------------------

typedef unsigned short u16;
typedef __attribute__((ext_vector_type(8))) short bf16x8;
typedef __attribute__((ext_vector_type(4))) float f32x4;

#define MFMA16(a, b, c) __builtin_amdgcn_mfma_f32_16x16x32_bf16((a), (b), (c), 0, 0, 0)

#define NC 262144ull            // 1024*256
#define REG 8388608ull          // 32*NC
#define OFF_X1T  0ull
#define OFF_X2T  (REG)
#define OFF_Q1T  (2ull*REG)
#define OFF_K1T  (3ull*REG)
#define OFF_Q2T  (4ull*REG)
#define OFF_K2T  (5ull*REG)
#define OFF_V    (6ull*REG)
#define WS_NEED_BYTES (7ull*REG*2)

// bf16 weights: 0 Wq, 1 Wk, 2 Wv, 3 Wps, 4 Wpc  (converted once in ktp)
__device__ __align__(16) u16 g_wb[5][65536];

__device__ __forceinline__ u16 f2b(float f) {
    union { float f; unsigned int i; } v; v.f = f;
    unsigned int r = (v.i + 0x7FFFu + ((v.i >> 16) & 1u)) >> 16;
    return (u16)r;
}

// async global->LDS DMA, 16 B per lane. lptr must be wave-uniform; HW adds
// lane*16. gptr is per-lane.
__device__ __forceinline__ void gload16(const u16* g, u16* l) {
    __builtin_amdgcn_global_load_lds(
        (const __attribute__((address_space(1))) void*)g,
        (__attribute__((address_space(3))) void*)l,
        16, 0, 0);
}

__global__ void ksig(float* out, float val) {
    if (threadIdx.x == 0 && blockIdx.x == 0) out[0] = val;
}

// ---------------------------------------------------------------------------
// ktp: merged ktrans + kprep. grid 4416, block 256.
//  blk < 4096:  X[b][c][n] fp32 -> XT[b][n][c] bf16   (16 nt x 4 ct x 64 bz)
//  blk >= 4096: 5x 256x256 fp32 weights -> bf16 g_wb  (320 blocks)
// ---------------------------------------------------------------------------
__global__ __launch_bounds__(256) void ktp(
    const float* __restrict__ x1, const float* __restrict__ x2,
    const float* __restrict__ Wq, const float* __restrict__ Wk,
    const float* __restrict__ Wv, const float* __restrict__ Wps,
    const float* __restrict__ Wpc, u16* __restrict__ ws)
{
    __shared__ __align__(16) u16 tile[64][68];
    int t = threadIdx.x;
    if (blockIdx.x >= 4096) {
        int blk = blockIdx.x - 4096;
        int w = blk >> 6, j = blk & 63;
        const float* src = (w == 0) ? Wq : (w == 1) ? Wk : (w == 2) ? Wv : (w == 3) ? Wps : Wpc;
        int idx = j * 1024 + t * 4;
        float4 v = *(const float4*)(src + idx);
        ushort4 o;
        o.x = f2b(v.x); o.y = f2b(v.y); o.z = f2b(v.z); o.w = f2b(v.w);
        *(ushort4*)&g_wb[w][idx] = o;
        return;
    }
    int blk = blockIdx.x;
    int nt = blk & 15, ct = (blk >> 4) & 3, bz = blk >> 6;
    int b = bz >> 1, which = bz & 1;
    const float* X = (which ? x2 : x1) + (size_t)b * NC;
    u16* XT = ws + (which ? OFF_X2T : OFF_X1T) + (size_t)b * NC;
    int c0 = ct * 64, n0 = nt * 64;

    int tn = t & 15, tc = t >> 4;
#pragma unroll
    for (int j = 0; j < 4; ++j) {
        float4 v = *(const float4*)(X + (size_t)(c0 + 4 * tc + j) * 1024 + n0 + 4 * tn);
        u16* d = &tile[4 * tc + j][4 * tn];
        d[0] = f2b(v.x); d[1] = f2b(v.y); d[2] = f2b(v.z); d[3] = f2b(v.w);
    }
    __syncthreads();
    int tcB = t & 15, tnB = t >> 4;
#pragma unroll
    for (int i = 0; i < 4; ++i) {
        ushort4 o;
        o.x = tile[4 * tcB + 0][4 * tnB + i];
        o.y = tile[4 * tcB + 1][4 * tnB + i];
        o.z = tile[4 * tcB + 2][4 * tnB + i];
        o.w = tile[4 * tcB + 3][4 * tnB + i];
        *(ushort4*)(XT + (size_t)(n0 + 4 * tnB + i) * 256 + c0 + 4 * tcB) = o;
    }
}

// ---------------------------------------------------------------------------
// gemm_core (verified r10): C[128x128] = A[m][256] * B[n][256]^T (+bias).
// Pure bf16, async DMA staging, BK=32 dbuf, 1 barrier/K-step.
// ---------------------------------------------------------------------------
__device__ __forceinline__ void gemm_core(
    const u16* __restrict__ A, const u16* __restrict__ B,
    int m0, int n0,
    u16* __restrict__ C, int ldc,
    const float* __restrict__ bias, int biasPerRow)
{
    __shared__ __align__(16) u16 As[2][4096];   // [buf][128*32]
    __shared__ __align__(16) u16 Bs[2][4096];
    int t = threadIdx.x;
    int lane = t & 63, wave = t >> 6;
    int wm = wave >> 1, wn = wave & 1;
    int col = lane & 15, quad = lane >> 4;

    f32x4 acc[4][4];
#pragma unroll
    for (int i = 0; i < 4; ++i)
#pragma unroll
        for (int j = 0; j < 4; ++j) acc[i][j] = f32x4{0.f, 0.f, 0.f, 0.f};

    int rA = t >> 2;
    int lA = (((t & 3) ^ ((t >> 3) & 3)) << 3);        // u16 offset in row
    const u16* aB = A + (size_t)(m0 + rA) * 256 + lA;
    const u16* bB = B + (size_t)(n0 + rA) * 256 + lA;
    int ldsw = wave * 512;                              // u16

    int rchunk = ((quad ^ ((col >> 1) & 3)) << 3);

    gload16(aB,          &As[0][ldsw]);
    gload16(aB + 16384,  &As[0][ldsw + 2048]);
    gload16(bB,          &Bs[0][ldsw]);
    gload16(bB + 16384,  &Bs[0][ldsw + 2048]);

    for (int kt = 0; kt < 8; ++kt) {
        int cur = kt & 1;
        __syncthreads();          // vmcnt drain: slab kt resident
        if (kt < 7) {
            int off = (kt + 1) * 32;
            gload16(aB + off,          &As[cur ^ 1][ldsw]);
            gload16(aB + off + 16384,  &As[cur ^ 1][ldsw + 2048]);
            gload16(bB + off,          &Bs[cur ^ 1][ldsw]);
            gload16(bB + off + 16384,  &Bs[cur ^ 1][ldsw + 2048]);
        }

        bf16x8 af[4], bf[4];
#pragma unroll
        for (int mf = 0; mf < 4; ++mf)
            af[mf] = *(const bf16x8*)&As[cur][(wm * 64 + mf * 16 + col) * 32 + rchunk];
#pragma unroll
        for (int nf = 0; nf < 4; ++nf)
            bf[nf] = *(const bf16x8*)&Bs[cur][(wn * 64 + nf * 16 + col) * 32 + rchunk];
        __builtin_amdgcn_s_setprio(1);
#pragma unroll
        for (int mf = 0; mf < 4; ++mf)
#pragma unroll
            for (int nf = 0; nf < 4; ++nf)
                acc[mf][nf] = MFMA16(af[mf], bf[nf], acc[mf][nf]);
        __builtin_amdgcn_s_setprio(0);
    }

#pragma unroll
    for (int mf = 0; mf < 4; ++mf)
#pragma unroll
        for (int nf = 0; nf < 4; ++nf) {
            int gm = m0 + wm * 64 + mf * 16 + quad * 4;
            int gn = n0 + wn * 64 + nf * 16 + col;
            float bcol = biasPerRow ? 0.f : bias[gn];
#pragma unroll
            for (int r = 0; r < 4; ++r) {
                int row = gm + r;
                float hv = acc[mf][nf][r] + (biasPerRow ? bias[row] : bcol);
                C[(size_t)row * ldc + gn] = f2b(hv);
            }
        }
}

// ---------------------------------------------------------------------------
// kproj: 5 projections per batch. 1-D grid 2560, XCD-clustered, block 256.
// ---------------------------------------------------------------------------
__global__ __launch_bounds__(256) void kproj(
    const float* __restrict__ bq, const float* __restrict__ bk,
    const float* __restrict__ bv, u16* __restrict__ ws)
{
    int blk = blockIdx.x;
    int xcd = blk & 7, jj = blk >> 3;       // jj 0..319
    int bg = jj / 80, id = jj % 80;
    int b = bg * 8 + xcd;                   // batches serialize per XCD
    const u16* X1T = ws + OFF_X1T + (size_t)b * NC;
    const u16* X2T = ws + OFF_X2T + (size_t)b * NC;
    if (id < 64) {
        int out = id >> 4, tt = id & 15, mt = tt >> 1, nt = tt & 1;
        const u16* A = (out < 2) ? X1T : X2T;
        const u16* W = (out & 1) ? &g_wb[1][0] : &g_wb[0][0];
        const float* bb = (out & 1) ? bk : bq;
        size_t off = (out == 0) ? OFF_Q1T : (out == 1) ? OFF_K1T : (out == 2) ? OFF_Q2T : OFF_K2T;
        u16* C = ws + off + (size_t)b * NC;
        gemm_core(A, W, mt * 128, nt * 128, C, 256, bb, 0);
    } else {
        int tt = id - 64, mt = tt >> 3, nt = tt & 7;
        u16* C = ws + OFF_V + (size_t)b * NC;
        gemm_core(&g_wb[2][0], X1T, mt * 128, nt * 128, C, 1024, bv, 1);
    }
}

// ---------------------------------------------------------------------------
// kattn v6: grid 256 (XCD-clustered), block 512 = 8 waves x 16 queries.
// Main loop with counted-vmcnt double-barrier sync (prefetch survives).
// Fused output-projection epilogue (verified r10).
// LDS pool aliased: main 105 KB; epilogue HS[128][264] @0.
// ---------------------------------------------------------------------------
__global__ __launch_bounds__(512, 2) void kattn(
    u16* __restrict__ ws, const float* __restrict__ x1,
    const float* __restrict__ bps, const float* __restrict__ bpc,
    float* __restrict__ out)
{
    int blk = blockIdx.x;
    int xcd = blk & 7, jj = blk >> 3;        // jj 0..31
    int b = ((jj >> 3) << 3) + xcd;          // 4 batch-groups, serialized per XCD
    int qt = jj & 7;                         // 8 q-tiles of 128 queries
    int t = threadIdx.x, lane = t & 63, wave = t >> 6;   // wave 0..7
    int col = lane & 15, quad = lane >> 4;

    const u16* Q1T = ws + OFF_Q1T + (size_t)b * NC;
    const u16* K1T = ws + OFF_K1T + (size_t)b * NC;
    const u16* Q2T = ws + OFF_Q2T + (size_t)b * NC;
    const u16* K2T = ws + OFF_K2T + (size_t)b * NC;
    const u16* V   = ws + OFF_V   + (size_t)b * NC;

    __shared__ __align__(16) u16 SH[53760];
    u16* K1s0 = SH;            // [2][8192]
    u16* K2s0 = SH + 16384;    // [2][8192]
    u16* Vs0  = SH + 32768;    // [2][8192]
    u16* P    = SH + 49152 + wave * 576;

    int i0 = qt * 128 + wave * 16;

    // Q fragments in registers: A[m=col][k = f*32 + quad*8 + j]
    bf16x8 aq1[8], aq2[8];
#pragma unroll
    for (int f = 0; f < 8; ++f) {
        aq1[f] = *(const bf16x8*)(Q1T + (size_t)(i0 + col) * 256 + f * 32 + quad * 8);
        aq2[f] = *(const bf16x8*)(Q2T + (size_t)(i0 + col) * 256 + f * 32 + quad * 8);
    }

    f32x4 h1[16], h12[16];
#pragma unroll
    for (int cf = 0; cf < 16; ++cf) { h1[cf] = f32x4{0.f,0.f,0.f,0.f}; h12[cf] = f32x4{0.f,0.f,0.f,0.f}; }
    float l1p[4], l2p[4];
#pragma unroll
    for (int r = 0; r < 4; ++r) { l1p[r] = 0.f; l2p[r] = 0.f; }

    const float sc = 0.0901684400555602f;   // log2(e)/16
    const float SH_ = 5.770780163555851f;   // 4*log2(e): fixed shift, overflow-safe

    // ---- staging geometry (loop-invariant per thread) ----
    int kr_ = t >> 5;                        // key row, shot 0
    int kwb = (t & 31) << 4;                 // stored byte offset
    int kwl = kwb ^ ((kr_ & 7) << 4);        // logical (source) byte offset
    const u16* k1src = K1T + (size_t)kr_ * 256 + (kwl >> 1);
    const u16* k2src = K2T + (size_t)kr_ * 256 + (kwl >> 1);
    int vrow = t >> 2;                       // channel, shot 0
    int vo = (t & 3) << 3;
    const u16* vsrc = V + (size_t)vrow * 1024 + vo;
    int ldsw = wave * 512;                   // wave-uniform LDS base (u16)

    // ---- prologue: async-stage tile 0 into buffer 0 ----
    gload16(k1src,          K1s0 + ldsw);
    gload16(k1src + 4096,   K1s0 + ldsw + 4096);
    gload16(k2src,          K2s0 + ldsw);
    gload16(k2src + 4096,   K2s0 + ldsw + 4096);
    gload16(vsrc,           Vs0 + ldsw);
    gload16(vsrc + 131072,  Vs0 + ldsw + 4096);

    int swz = (col & 7) << 3;                // read-side XOR, u16 units

    for (int it = 0; it < 32; ++it) {
        int cur = it & 1;

        // barrier #1: all waves done reading buf[cur^1] (tile it-1) -> free
        __builtin_amdgcn_sched_barrier(0);
        __builtin_amdgcn_s_barrier();

        // ---- issue tile it+1 DMAs into buf[cur^1]; keep them in flight ----
        if (it < 31) {
            int nxt = (cur ^ 1) * 8192;
            const u16* s1 = k1src + (size_t)(it + 1) * 8192;   // +32 key rows
            const u16* s2 = k2src + (size_t)(it + 1) * 8192;
            const u16* sv = vsrc + (size_t)(it + 1) * 32;      // +32 keys
            gload16(s1,          K1s0 + nxt + ldsw);
            gload16(s1 + 4096,   K1s0 + nxt + ldsw + 4096);
            gload16(s2,          K2s0 + nxt + ldsw);
            gload16(s2 + 4096,   K2s0 + nxt + ldsw + 4096);
            gload16(sv,          Vs0 + nxt + ldsw);
            gload16(sv + 131072, Vs0 + nxt + ldsw + 4096);
            // own tile-it loads done (6 newest = tile it+1 stay in flight)
            asm volatile("s_waitcnt vmcnt(6)" ::: "memory");
        } else {
            asm volatile("s_waitcnt vmcnt(0)" ::: "memory");
        }
        __builtin_amdgcn_sched_barrier(0);
        // barrier #2: every wave's tile-it loads have landed in LDS
        __builtin_amdgcn_s_barrier();
        __builtin_amdgcn_sched_barrier(0);

        const u16* K1c = K1s0 + cur * 8192;
        const u16* K2c = K2s0 + cur * 8192;
        const u16* Vc  = Vs0 + cur * 8192;

        // ---- QK: S1, S2 : D[row=quad*4+r (query)][col (key)] ----
        f32x4 s1v[2], s2v[2];
        s1v[0] = s1v[1] = s2v[0] = s2v[1] = f32x4{0.f,0.f,0.f,0.f};
        __builtin_amdgcn_s_setprio(1);
#pragma unroll
        for (int nf = 0; nf < 2; ++nf) {
            int krow = nf * 16 + col;
#pragma unroll
            for (int f = 0; f < 8; ++f) {
                int wb = (f * 32 + quad * 8) ^ swz;            // swizzled u16 off
                bf16x8 bk1 = *(const bf16x8*)&K1c[krow * 256 + wb];
                s1v[nf] = MFMA16(aq1[f], bk1, s1v[nf]);
                bf16x8 bk2 = *(const bf16x8*)&K2c[krow * 256 + wb];
                s2v[nf] = MFMA16(aq2[f], bk2, s2v[nf]);
            }
        }
        __builtin_amdgcn_s_setprio(0);

        // ---- fixed-shift softmax, branch 1 -> P, pull frag ----
#pragma unroll
        for (int r = 0; r < 4; ++r) {
            float p0 = __builtin_amdgcn_exp2f(s1v[0][r] * sc - SH_);
            float p1 = __builtin_amdgcn_exp2f(s1v[1][r] * sc - SH_);
            l1p[r] += p0 + p1;
            P[(quad * 4 + r) * 36 + col] = f2b(p0);
            P[(quad * 4 + r) * 36 + 16 + col] = f2b(p1);
        }
        bf16x8 p1f = *(const bf16x8*)&P[col * 36 + quad * 8];

        // ---- branch 12 (reuses P region; within-wave DS is in-order) ----
#pragma unroll
        for (int r = 0; r < 4; ++r) {
            float s0 = s1v[0][r] + s2v[0][r];
            float s1x = s1v[1][r] + s2v[1][r];
            float p0 = __builtin_amdgcn_exp2f(s0 * sc - SH_);
            float p1 = __builtin_amdgcn_exp2f(s1x * sc - SH_);
            l2p[r] += p0 + p1;
            P[(quad * 4 + r) * 36 + col] = f2b(p0);
            P[(quad * 4 + r) * 36 + 16 + col] = f2b(p1);
        }
        bf16x8 p2f = *(const bf16x8*)&P[col * 36 + quad * 8];

        // ---- PV: shared V-frag for both branches ----
        __builtin_amdgcn_s_setprio(1);
#pragma unroll
        for (int cf = 0; cf < 16; ++cf) {
            bf16x8 bv = *(const bf16x8*)&Vc[(cf * 16 + col) * 32 + quad * 8];
            h1[cf] = MFMA16(p1f, bv, h1[cf]);
            h12[cf] = MFMA16(p2f, bv, h12[cf]);
        }
        __builtin_amdgcn_s_setprio(0);
    }

    // ---- finalize: reduce l across the 16 col-lanes of each quad-row ----
    float inv1[4], inv2[4];
#pragma unroll
    for (int r = 0; r < 4; ++r) {
        float s = l1p[r];
        s += __shfl_xor(s, 1); s += __shfl_xor(s, 2);
        s += __shfl_xor(s, 4); s += __shfl_xor(s, 8);
        inv1[r] = 1.f / s;
        float s2x = l2p[r];
        s2x += __shfl_xor(s2x, 1); s2x += __shfl_xor(s2x, 2);
        s2x += __shfl_xor(s2x, 4); s2x += __shfl_xor(s2x, 8);
        inv2[r] = 1.f / s2x;
    }

    // ---- fused output projections: out = x1 + clamp(bias + W * H) ----
    u16* HS = SH;
    const int HROW = 264;
    const float* x1b = x1 + (size_t)b * NC;

    auto outproj = [&](const u16* __restrict__ W, const float* __restrict__ bb,
                       float* __restrict__ outp) {
        f32x4 oacc[2][8];
#pragma unroll
        for (int mf = 0; mf < 2; ++mf)
#pragma unroll
            for (int nf = 0; nf < 8; ++nf) oacc[mf][nf] = f32x4{0.f,0.f,0.f,0.f};
#pragma unroll
        for (int kf = 0; kf < 8; ++kf) {
            bf16x8 hb[8];
#pragma unroll
            for (int nf = 0; nf < 8; ++nf)
                hb[nf] = *(const bf16x8*)&HS[(nf * 16 + col) * HROW + kf * 32 + quad * 8];
#pragma unroll
            for (int mf = 0; mf < 2; ++mf) {
                bf16x8 wf = *(const bf16x8*)&W[(wave * 32 + mf * 16 + col) * 256 + kf * 32 + quad * 8];
#pragma unroll
                for (int nf = 0; nf < 8; ++nf)
                    oacc[mf][nf] = MFMA16(wf, hb[nf], oacc[mf][nf]);
            }
        }
#pragma unroll
        for (int mf = 0; mf < 2; ++mf)
#pragma unroll
            for (int r = 0; r < 4; ++r) {
                int o = wave * 32 + mf * 16 + quad * 4 + r;
                float bo = bb[o];
#pragma unroll
                for (int nf = 0; nf < 8; ++nf) {
                    int n = qt * 128 + nf * 16 + col;
                    size_t ci = (size_t)o * 1024 + n;
                    float hv = oacc[mf][nf][r] + bo;
                    hv = fminf(fmaxf(hv, -0.05f), 0.05f);
                    outp[ci] = hv + x1b[ci];
                }
            }
    };

    __syncthreads();    // all waves done with K/V LDS (full drain)
#pragma unroll
    for (int cf = 0; cf < 16; ++cf)
#pragma unroll
        for (int r = 0; r < 4; ++r)
            HS[(wave * 16 + quad * 4 + r) * HROW + cf * 16 + col] = f2b(h1[cf][r] * inv1[r]);
    __syncthreads();
    outproj(&g_wb[3][0], bps, out + (size_t)b * NC);
    __syncthreads();    // out1 reads done; safe to overwrite HS
#pragma unroll
    for (int cf = 0; cf < 16; ++cf)
#pragma unroll
        for (int r = 0; r < 4; ++r)
            HS[(wave * 16 + quad * 4 + r) * HROW + cf * 16 + col] = f2b(h12[cf][r] * inv2[r]);
    __syncthreads();
    outproj(&g_wb[4][0], bpc, out + REG + (size_t)b * NC);
}

// ---------------------------------------------------------------------------
extern "C" void kernel_launch(void* const* d_in, const int* in_sizes, int n_in,
                              void* d_out, int out_size, void* d_ws, size_t ws_size,
                              hipStream_t stream)
{
    float* out = (float*)d_out;
    u16* ws = (u16*)d_ws;

    if (ws_size < WS_NEED_BYTES) { ksig<<<1, 64, 0, stream>>>(out, 1.0e7f); return; }
    if (n_in != 12 || in_sizes[0] != 8388608 || in_sizes[1] != 8388608 ||
        in_sizes[2] != 65536 || in_sizes[3] != 256 || out_size != 16777216) {
        ksig<<<1, 64, 0, stream>>>(out, 5.0e6f); return;
    }

    const float* x1  = (const float*)d_in[0];
    const float* x2  = (const float*)d_in[1];
    const float* Wq  = (const float*)d_in[2];
    const float* bq  = (const float*)d_in[3];
    const float* Wk  = (const float*)d_in[4];
    const float* bk  = (const float*)d_in[5];
    const float* Wv  = (const float*)d_in[6];
    const float* bv  = (const float*)d_in[7];
    const float* Wps = (const float*)d_in[8];
    const float* bps = (const float*)d_in[9];
    const float* Wpc = (const float*)d_in[10];
    const float* bpc = (const float*)d_in[11];

    ktp<<<4416, 256, 0, stream>>>(x1, x2, Wq, Wk, Wv, Wps, Wpc, ws);
    kproj<<<2560, 256, 0, stream>>>(bq, bk, bv, ws);
    kattn<<<256, 512, 0, stream>>>(ws, x1, bps, bpc, out);
}

// Round 10
// 278.822 us; speedup vs baseline: 1.0500x; 1.0500x over previous
//
#include <hip/hip_runtime.h>

// ---------------------------------------------------------------------------
// SpatialSelfCrossAttention  (B=32, C=256, H=W=32, N=1024)
// I/O fp32, internal bf16 MFMA (fp32 accum).
//
// Round-14 changes (kattn only; r9 counted-vmcnt reverted - it regressed):
//  * Main-loop sync back to r8 __syncthreads() (verified 126 us state).
//  * V LDS tile now chunk-XOR swizzled (stored 16B chunk = logical ^
//    ((ch>>1)&3); DMA source pre-swizzled, read applies same XOR). The
//    unswizzled 64B-stride V rows were an 8-distinct-address bank-group
//    collision (~2.9x) on all 128 V-reads/iter - the bulk of the 1.36e7
//    SQ_LDS_BANK_CONFLICT.
//  * P row stride 36 -> 40 u16: P pulls become aligned ds_read_b128 with
//    2-lane/bank-group pattern (free).
//  * ktp / kproj / epilogue unchanged.
// ---------------------------------------------------------------------------

typedef unsigned short u16;
typedef __attribute__((ext_vector_type(8))) short bf16x8;
typedef __attribute__((ext_vector_type(4))) float f32x4;

#define MFMA16(a, b, c) __builtin_amdgcn_mfma_f32_16x16x32_bf16((a), (b), (c), 0, 0, 0)

#define NC 262144ull            // 1024*256
#define REG 8388608ull          // 32*NC
#define OFF_X1T  0ull
#define OFF_X2T  (REG)
#define OFF_Q1T  (2ull*REG)
#define OFF_K1T  (3ull*REG)
#define OFF_Q2T  (4ull*REG)
#define OFF_K2T  (5ull*REG)
#define OFF_V    (6ull*REG)
#define WS_NEED_BYTES (7ull*REG*2)

// bf16 weights: 0 Wq, 1 Wk, 2 Wv, 3 Wps, 4 Wpc  (converted once in ktp)
__device__ __align__(16) u16 g_wb[5][65536];

__device__ __forceinline__ u16 f2b(float f) {
    union { float f; unsigned int i; } v; v.f = f;
    unsigned int r = (v.i + 0x7FFFu + ((v.i >> 16) & 1u)) >> 16;
    return (u16)r;
}

// async global->LDS DMA, 16 B per lane. lptr must be wave-uniform; HW adds
// lane*16. gptr is per-lane.
__device__ __forceinline__ void gload16(const u16* g, u16* l) {
    __builtin_amdgcn_global_load_lds(
        (const __attribute__((address_space(1))) void*)g,
        (__attribute__((address_space(3))) void*)l,
        16, 0, 0);
}

__global__ void ksig(float* out, float val) {
    if (threadIdx.x == 0 && blockIdx.x == 0) out[0] = val;
}

// ---------------------------------------------------------------------------
// ktp: merged ktrans + kprep. grid 4416, block 256.
//  blk < 4096:  X[b][c][n] fp32 -> XT[b][n][c] bf16   (16 nt x 4 ct x 64 bz)
//  blk >= 4096: 5x 256x256 fp32 weights -> bf16 g_wb  (320 blocks)
// ---------------------------------------------------------------------------
__global__ __launch_bounds__(256) void ktp(
    const float* __restrict__ x1, const float* __restrict__ x2,
    const float* __restrict__ Wq, const float* __restrict__ Wk,
    const float* __restrict__ Wv, const float* __restrict__ Wps,
    const float* __restrict__ Wpc, u16* __restrict__ ws)
{
    __shared__ __align__(16) u16 tile[64][68];
    int t = threadIdx.x;
    if (blockIdx.x >= 4096) {
        int blk = blockIdx.x - 4096;
        int w = blk >> 6, j = blk & 63;
        const float* src = (w == 0) ? Wq : (w == 1) ? Wk : (w == 2) ? Wv : (w == 3) ? Wps : Wpc;
        int idx = j * 1024 + t * 4;
        float4 v = *(const float4*)(src + idx);
        ushort4 o;
        o.x = f2b(v.x); o.y = f2b(v.y); o.z = f2b(v.z); o.w = f2b(v.w);
        *(ushort4*)&g_wb[w][idx] = o;
        return;
    }
    int blk = blockIdx.x;
    int nt = blk & 15, ct = (blk >> 4) & 3, bz = blk >> 6;
    int b = bz >> 1, which = bz & 1;
    const float* X = (which ? x2 : x1) + (size_t)b * NC;
    u16* XT = ws + (which ? OFF_X2T : OFF_X1T) + (size_t)b * NC;
    int c0 = ct * 64, n0 = nt * 64;

    int tn = t & 15, tc = t >> 4;
#pragma unroll
    for (int j = 0; j < 4; ++j) {
        float4 v = *(const float4*)(X + (size_t)(c0 + 4 * tc + j) * 1024 + n0 + 4 * tn);
        u16* d = &tile[4 * tc + j][4 * tn];
        d[0] = f2b(v.x); d[1] = f2b(v.y); d[2] = f2b(v.z); d[3] = f2b(v.w);
    }
    __syncthreads();
    int tcB = t & 15, tnB = t >> 4;
#pragma unroll
    for (int i = 0; i < 4; ++i) {
        ushort4 o;
        o.x = tile[4 * tcB + 0][4 * tnB + i];
        o.y = tile[4 * tcB + 1][4 * tnB + i];
        o.z = tile[4 * tcB + 2][4 * tnB + i];
        o.w = tile[4 * tcB + 3][4 * tnB + i];
        *(ushort4*)(XT + (size_t)(n0 + 4 * tnB + i) * 256 + c0 + 4 * tcB) = o;
    }
}

// ---------------------------------------------------------------------------
// gemm_core (verified r10): C[128x128] = A[m][256] * B[n][256]^T (+bias).
// Pure bf16, async DMA staging, BK=32 dbuf, 1 barrier/K-step.
// ---------------------------------------------------------------------------
__device__ __forceinline__ void gemm_core(
    const u16* __restrict__ A, const u16* __restrict__ B,
    int m0, int n0,
    u16* __restrict__ C, int ldc,
    const float* __restrict__ bias, int biasPerRow)
{
    __shared__ __align__(16) u16 As[2][4096];   // [buf][128*32]
    __shared__ __align__(16) u16 Bs[2][4096];
    int t = threadIdx.x;
    int lane = t & 63, wave = t >> 6;
    int wm = wave >> 1, wn = wave & 1;
    int col = lane & 15, quad = lane >> 4;

    f32x4 acc[4][4];
#pragma unroll
    for (int i = 0; i < 4; ++i)
#pragma unroll
        for (int j = 0; j < 4; ++j) acc[i][j] = f32x4{0.f, 0.f, 0.f, 0.f};

    int rA = t >> 2;
    int lA = (((t & 3) ^ ((t >> 3) & 3)) << 3);        // u16 offset in row
    const u16* aB = A + (size_t)(m0 + rA) * 256 + lA;
    const u16* bB = B + (size_t)(n0 + rA) * 256 + lA;
    int ldsw = wave * 512;                              // u16

    int rchunk = ((quad ^ ((col >> 1) & 3)) << 3);

    gload16(aB,          &As[0][ldsw]);
    gload16(aB + 16384,  &As[0][ldsw + 2048]);
    gload16(bB,          &Bs[0][ldsw]);
    gload16(bB + 16384,  &Bs[0][ldsw + 2048]);

    for (int kt = 0; kt < 8; ++kt) {
        int cur = kt & 1;
        __syncthreads();          // vmcnt drain: slab kt resident
        if (kt < 7) {
            int off = (kt + 1) * 32;
            gload16(aB + off,          &As[cur ^ 1][ldsw]);
            gload16(aB + off + 16384,  &As[cur ^ 1][ldsw + 2048]);
            gload16(bB + off,          &Bs[cur ^ 1][ldsw]);
            gload16(bB + off + 16384,  &Bs[cur ^ 1][ldsw + 2048]);
        }

        bf16x8 af[4], bf[4];
#pragma unroll
        for (int mf = 0; mf < 4; ++mf)
            af[mf] = *(const bf16x8*)&As[cur][(wm * 64 + mf * 16 + col) * 32 + rchunk];
#pragma unroll
        for (int nf = 0; nf < 4; ++nf)
            bf[nf] = *(const bf16x8*)&Bs[cur][(wn * 64 + nf * 16 + col) * 32 + rchunk];
        __builtin_amdgcn_s_setprio(1);
#pragma unroll
        for (int mf = 0; mf < 4; ++mf)
#pragma unroll
            for (int nf = 0; nf < 4; ++nf)
                acc[mf][nf] = MFMA16(af[mf], bf[nf], acc[mf][nf]);
        __builtin_amdgcn_s_setprio(0);
    }

#pragma unroll
    for (int mf = 0; mf < 4; ++mf)
#pragma unroll
        for (int nf = 0; nf < 4; ++nf) {
            int gm = m0 + wm * 64 + mf * 16 + quad * 4;
            int gn = n0 + wn * 64 + nf * 16 + col;
            float bcol = biasPerRow ? 0.f : bias[gn];
#pragma unroll
            for (int r = 0; r < 4; ++r) {
                int row = gm + r;
                float hv = acc[mf][nf][r] + (biasPerRow ? bias[row] : bcol);
                C[(size_t)row * ldc + gn] = f2b(hv);
            }
        }
}

// ---------------------------------------------------------------------------
// kproj: 5 projections per batch. 1-D grid 2560, XCD-clustered, block 256.
// ---------------------------------------------------------------------------
__global__ __launch_bounds__(256) void kproj(
    const float* __restrict__ bq, const float* __restrict__ bk,
    const float* __restrict__ bv, u16* __restrict__ ws)
{
    int blk = blockIdx.x;
    int xcd = blk & 7, jj = blk >> 3;       // jj 0..319
    int bg = jj / 80, id = jj % 80;
    int b = bg * 8 + xcd;                   // batches serialize per XCD
    const u16* X1T = ws + OFF_X1T + (size_t)b * NC;
    const u16* X2T = ws + OFF_X2T + (size_t)b * NC;
    if (id < 64) {
        int out = id >> 4, tt = id & 15, mt = tt >> 1, nt = tt & 1;
        const u16* A = (out < 2) ? X1T : X2T;
        const u16* W = (out & 1) ? &g_wb[1][0] : &g_wb[0][0];
        const float* bb = (out & 1) ? bk : bq;
        size_t off = (out == 0) ? OFF_Q1T : (out == 1) ? OFF_K1T : (out == 2) ? OFF_Q2T : OFF_K2T;
        u16* C = ws + off + (size_t)b * NC;
        gemm_core(A, W, mt * 128, nt * 128, C, 256, bb, 0);
    } else {
        int tt = id - 64, mt = tt >> 3, nt = tt & 7;
        u16* C = ws + OFF_V + (size_t)b * NC;
        gemm_core(&g_wb[2][0], X1T, mt * 128, nt * 128, C, 1024, bv, 1);
    }
}

// ---------------------------------------------------------------------------
// kattn v7: grid 256 (XCD-clustered), block 512 = 8 waves x 16 queries.
// r8 sync structure (one __syncthreads per iter). V tile chunk-XOR swizzled;
// P stride 40 (aligned b128 pulls). Fused output-projection epilogue.
// LDS pool aliased: main 108.5 KB; epilogue HS[128][264] @0.
// ---------------------------------------------------------------------------
__global__ __launch_bounds__(512, 2) void kattn(
    u16* __restrict__ ws, const float* __restrict__ x1,
    const float* __restrict__ bps, const float* __restrict__ bpc,
    float* __restrict__ out)
{
    int blk = blockIdx.x;
    int xcd = blk & 7, jj = blk >> 3;        // jj 0..31
    int b = ((jj >> 3) << 3) + xcd;          // 4 batch-groups, serialized per XCD
    int qt = jj & 7;                         // 8 q-tiles of 128 queries
    int t = threadIdx.x, lane = t & 63, wave = t >> 6;   // wave 0..7
    int col = lane & 15, quad = lane >> 4;

    const u16* Q1T = ws + OFF_Q1T + (size_t)b * NC;
    const u16* K1T = ws + OFF_K1T + (size_t)b * NC;
    const u16* Q2T = ws + OFF_Q2T + (size_t)b * NC;
    const u16* K2T = ws + OFF_K2T + (size_t)b * NC;
    const u16* V   = ws + OFF_V   + (size_t)b * NC;

    __shared__ __align__(16) u16 SH[54272];
    u16* K1s0 = SH;            // [2][8192]
    u16* K2s0 = SH + 16384;    // [2][8192]
    u16* Vs0  = SH + 32768;    // [2][8192]
    u16* P    = SH + 49152 + wave * 640;    // [16][40]

    int i0 = qt * 128 + wave * 16;

    // Q fragments in registers: A[m=col][k = f*32 + quad*8 + j]
    bf16x8 aq1[8], aq2[8];
#pragma unroll
    for (int f = 0; f < 8; ++f) {
        aq1[f] = *(const bf16x8*)(Q1T + (size_t)(i0 + col) * 256 + f * 32 + quad * 8);
        aq2[f] = *(const bf16x8*)(Q2T + (size_t)(i0 + col) * 256 + f * 32 + quad * 8);
    }

    f32x4 h1[16], h12[16];
#pragma unroll
    for (int cf = 0; cf < 16; ++cf) { h1[cf] = f32x4{0.f,0.f,0.f,0.f}; h12[cf] = f32x4{0.f,0.f,0.f,0.f}; }
    float l1p[4], l2p[4];
#pragma unroll
    for (int r = 0; r < 4; ++r) { l1p[r] = 0.f; l2p[r] = 0.f; }

    const float sc = 0.0901684400555602f;   // log2(e)/16
    const float SH_ = 5.770780163555851f;   // 4*log2(e): fixed shift, overflow-safe

    // ---- staging geometry (loop-invariant per thread) ----
    int kr_ = t >> 5;                        // key row, shot 0
    int kwb = (t & 31) << 4;                 // stored byte offset
    int kwl = kwb ^ ((kr_ & 7) << 4);        // logical (source) byte offset
    const u16* k1src = K1T + (size_t)kr_ * 256 + (kwl >> 1);
    const u16* k2src = K2T + (size_t)kr_ * 256 + (kwl >> 1);
    // V: stored chunk t&3 of row vrow holds logical chunk (t&3)^((vrow>>1)&3)
    int vrow = t >> 2;                       // channel, shot 0 (shot1: +128, swz same)
    int vo = (((t & 3) ^ ((vrow >> 1) & 3)) << 3);     // pre-swizzled source off
    const u16* vsrc = V + (size_t)vrow * 1024 + vo;
    int ldsw = wave * 512;                   // wave-uniform LDS base (u16)

    // ---- prologue: async-stage tile 0 into buffer 0 ----
    gload16(k1src,          K1s0 + ldsw);
    gload16(k1src + 4096,   K1s0 + ldsw + 4096);
    gload16(k2src,          K2s0 + ldsw);
    gload16(k2src + 4096,   K2s0 + ldsw + 4096);
    gload16(vsrc,           Vs0 + ldsw);
    gload16(vsrc + 131072,  Vs0 + ldsw + 4096);

    int swz = (col & 7) << 3;                // K read-side XOR, u16 units
    int vrd = ((quad ^ ((col >> 1) & 3)) << 3);  // V read-side chunk XOR, u16

    for (int it = 0; it < 32; ++it) {
        int cur = it & 1;
        __syncthreads();   // drains vmcnt (DMA of tile `it` done) + barrier

        // ---- async-stage tile it+1 into the other buffer ----
        if (it < 31) {
            int nxt = (cur ^ 1) * 8192;
            const u16* s1 = k1src + (size_t)(it + 1) * 8192;   // +32 key rows
            const u16* s2 = k2src + (size_t)(it + 1) * 8192;
            const u16* sv = vsrc + (size_t)(it + 1) * 32;      // +32 keys
            gload16(s1,          K1s0 + nxt + ldsw);
            gload16(s1 + 4096,   K1s0 + nxt + ldsw + 4096);
            gload16(s2,          K2s0 + nxt + ldsw);
            gload16(s2 + 4096,   K2s0 + nxt + ldsw + 4096);
            gload16(sv,          Vs0 + nxt + ldsw);
            gload16(sv + 131072, Vs0 + nxt + ldsw + 4096);
        }

        const u16* K1c = K1s0 + cur * 8192;
        const u16* K2c = K2s0 + cur * 8192;
        const u16* Vc  = Vs0 + cur * 8192;

        // ---- QK: S1, S2 : D[row=quad*4+r (query)][col (key)] ----
        f32x4 s1v[2], s2v[2];
        s1v[0] = s1v[1] = s2v[0] = s2v[1] = f32x4{0.f,0.f,0.f,0.f};
        __builtin_amdgcn_s_setprio(1);
#pragma unroll
        for (int nf = 0; nf < 2; ++nf) {
            int krow = nf * 16 + col;
#pragma unroll
            for (int f = 0; f < 8; ++f) {
                int wb = (f * 32 + quad * 8) ^ swz;            // swizzled u16 off
                bf16x8 bk1 = *(const bf16x8*)&K1c[krow * 256 + wb];
                s1v[nf] = MFMA16(aq1[f], bk1, s1v[nf]);
                bf16x8 bk2 = *(const bf16x8*)&K2c[krow * 256 + wb];
                s2v[nf] = MFMA16(aq2[f], bk2, s2v[nf]);
            }
        }
        __builtin_amdgcn_s_setprio(0);

        // ---- fixed-shift softmax, branch 1 -> P, pull frag ----
#pragma unroll
        for (int r = 0; r < 4; ++r) {
            float p0 = __builtin_amdgcn_exp2f(s1v[0][r] * sc - SH_);
            float p1 = __builtin_amdgcn_exp2f(s1v[1][r] * sc - SH_);
            l1p[r] += p0 + p1;
            P[(quad * 4 + r) * 40 + col] = f2b(p0);
            P[(quad * 4 + r) * 40 + 16 + col] = f2b(p1);
        }
        bf16x8 p1f = *(const bf16x8*)&P[col * 40 + quad * 8];

        // ---- branch 12 (reuses P region; within-wave DS is in-order) ----
#pragma unroll
        for (int r = 0; r < 4; ++r) {
            float s0 = s1v[0][r] + s2v[0][r];
            float s1x = s1v[1][r] + s2v[1][r];
            float p0 = __builtin_amdgcn_exp2f(s0 * sc - SH_);
            float p1 = __builtin_amdgcn_exp2f(s1x * sc - SH_);
            l2p[r] += p0 + p1;
            P[(quad * 4 + r) * 40 + col] = f2b(p0);
            P[(quad * 4 + r) * 40 + 16 + col] = f2b(p1);
        }
        bf16x8 p2f = *(const bf16x8*)&P[col * 40 + quad * 8];

        // ---- PV: shared V-frag for both branches (swizzled chunk) ----
        __builtin_amdgcn_s_setprio(1);
#pragma unroll
        for (int cf = 0; cf < 16; ++cf) {
            bf16x8 bv = *(const bf16x8*)&Vc[(cf * 16 + col) * 32 + vrd];
            h1[cf] = MFMA16(p1f, bv, h1[cf]);
            h12[cf] = MFMA16(p2f, bv, h12[cf]);
        }
        __builtin_amdgcn_s_setprio(0);
    }

    // ---- finalize: reduce l across the 16 col-lanes of each quad-row ----
    float inv1[4], inv2[4];
#pragma unroll
    for (int r = 0; r < 4; ++r) {
        float s = l1p[r];
        s += __shfl_xor(s, 1); s += __shfl_xor(s, 2);
        s += __shfl_xor(s, 4); s += __shfl_xor(s, 8);
        inv1[r] = 1.f / s;
        float s2x = l2p[r];
        s2x += __shfl_xor(s2x, 1); s2x += __shfl_xor(s2x, 2);
        s2x += __shfl_xor(s2x, 4); s2x += __shfl_xor(s2x, 8);
        inv2[r] = 1.f / s2x;
    }

    // ---- fused output projections: out = x1 + clamp(bias + W * H) ----
    u16* HS = SH;
    const int HROW = 264;
    const float* x1b = x1 + (size_t)b * NC;

    auto outproj = [&](const u16* __restrict__ W, const float* __restrict__ bb,
                       float* __restrict__ outp) {
        f32x4 oacc[2][8];
#pragma unroll
        for (int mf = 0; mf < 2; ++mf)
#pragma unroll
            for (int nf = 0; nf < 8; ++nf) oacc[mf][nf] = f32x4{0.f,0.f,0.f,0.f};
#pragma unroll
        for (int kf = 0; kf < 8; ++kf) {
            bf16x8 hb[8];
#pragma unroll
            for (int nf = 0; nf < 8; ++nf)
                hb[nf] = *(const bf16x8*)&HS[(nf * 16 + col) * HROW + kf * 32 + quad * 8];
#pragma unroll
            for (int mf = 0; mf < 2; ++mf) {
                bf16x8 wf = *(const bf16x8*)&W[(wave * 32 + mf * 16 + col) * 256 + kf * 32 + quad * 8];
#pragma unroll
                for (int nf = 0; nf < 8; ++nf)
                    oacc[mf][nf] = MFMA16(wf, hb[nf], oacc[mf][nf]);
            }
        }
#pragma unroll
        for (int mf = 0; mf < 2; ++mf)
#pragma unroll
            for (int r = 0; r < 4; ++r) {
                int o = wave * 32 + mf * 16 + quad * 4 + r;
                float bo = bb[o];
#pragma unroll
                for (int nf = 0; nf < 8; ++nf) {
                    int n = qt * 128 + nf * 16 + col;
                    size_t ci = (size_t)o * 1024 + n;
                    float hv = oacc[mf][nf][r] + bo;
                    hv = fminf(fmaxf(hv, -0.05f), 0.05f);
                    outp[ci] = hv + x1b[ci];
                }
            }
    };

    __syncthreads();    // all waves done with K/V LDS
#pragma unroll
    for (int cf = 0; cf < 16; ++cf)
#pragma unroll
        for (int r = 0; r < 4; ++r)
            HS[(wave * 16 + quad * 4 + r) * HROW + cf * 16 + col] = f2b(h1[cf][r] * inv1[r]);
    __syncthreads();
    outproj(&g_wb[3][0], bps, out + (size_t)b * NC);
    __syncthreads();    // out1 reads done; safe to overwrite HS
#pragma unroll
    for (int cf = 0; cf < 16; ++cf)
#pragma unroll
        for (int r = 0; r < 4; ++r)
            HS[(wave * 16 + quad * 4 + r) * HROW + cf * 16 + col] = f2b(h12[cf][r] * inv2[r]);
    __syncthreads();
    outproj(&g_wb[4][0], bpc, out + REG + (size_t)b * NC);
}

// ---------------------------------------------------------------------------
extern "C" void kernel_launch(void* const* d_in, const int* in_sizes, int n_in,
                              void* d_out, int out_size, void* d_ws, size_t ws_size,
                              hipStream_t stream)
{
    float* out = (float*)d_out;
    u16* ws = (u16*)d_ws;

    if (ws_size < WS_NEED_BYTES) { ksig<<<1, 64, 0, stream>>>(out, 1.0e7f); return; }
    if (n_in != 12 || in_sizes[0] != 8388608 || in_sizes[1] != 8388608 ||
        in_sizes[2] != 65536 || in_sizes[3] != 256 || out_size != 16777216) {
        ksig<<<1, 64, 0, stream>>>(out, 5.0e6f); return;
    }

    const float* x1  = (const float*)d_in[0];
    const float* x2  = (const float*)d_in[1];
    const float* Wq  = (const float*)d_in[2];
    const float* bq  = (const float*)d_in[3];
    const float* Wk  = (const float*)d_in[4];
    const float* bk  = (const float*)d_in[5];
    const float* Wv  = (const float*)d_in[6];
    const float* bv  = (const float*)d_in[7];
    const float* Wps = (const float*)d_in[8];
    const float* bps = (const float*)d_in[9];
    const float* Wpc = (const float*)d_in[10];
    const float* bpc = (const float*)d_in[11];

    ktp<<<4416, 256, 0, stream>>>(x1, x2, Wq, Wk, Wv, Wps, Wpc, ws);
    kproj<<<2560, 256, 0, stream>>>(bq, bk, bv, ws);
    kattn<<<256, 512, 0, stream>>>(ws, x1, bps, bpc, out);
}